// Round 1
// baseline (486.532 us; speedup 1.0000x reference)
//
#include <hip/hip_runtime.h>
#include <hip/hip_fp16.h>
#include <math.h>

#define HIDDEN 1024
#define CODE_LEN 10
#define NUM_TABLE 32
#define RPB 8            // rows per block (K1)
#define BSTR 36          // padded words per 32-elem block in LDS
#define RSTR (32*BSTR)   // 1152 words per row
#define TBL_ELEMS (32u*1024u*1024u)   // 33,554,432

__device__ __forceinline__ float4 f4(float a, float b, float c, float d) {
    return make_float4(a, b, c, d);
}

// ============================================================================
// K1: bit-exact LN/BH4/codes -> SC/CD in ws, with the fp32->fp16 table cast
// software-pipelined through the 4 BH4 stages (chunk issued one stage before
// its convert+store, so HBM cast traffic overlaps einsum VALU work).
// CAST=false variant used by the monolithic fallback path (computes+gathers fp32).
// ============================================================================
template <bool SPLIT>
__global__ __launch_bounds__(256, 4) void compute_kernel(
    const float* __restrict__ X,   // [rows,1024]
    const float* __restrict__ G,   // [1024] ln_gamma
    const float* __restrict__ Bt,  // [1024] ln_beta
    const float* __restrict__ W,   // [1,4,32,32,32] bh4_weight
    const float* __restrict__ ZB,  // [320] bh4_bias
    const float* __restrict__ TBL, // [32*1024,1024] tables flat (fp32)
    const float* __restrict__ OB,  // [1024] out_bias
    float* __restrict__ OUT,       // [rows,1024]
    __half* __restrict__ TBL16,    // ws: fp16 tables
    float* __restrict__ SC,        // ws: [rows*32] scores
    int*   __restrict__ CD)        // ws: [rows*32] codes
{
    __shared__ float lds[RPB * RSTR];          // 36864 B
    __shared__ float l_sc[RPB * NUM_TABLE];    // only used by !SPLIT path
    __shared__ int   l_cd[RPB * NUM_TABLE];

    const int t    = threadIdx.x;
    const int lane = t & 63;
    const int wv   = t >> 6;
    const int row0 = blockIdx.x * RPB;

    // ---------- Phase A: load raw x into padded LDS ----------
#pragma unroll
    for (int u = 0; u < 2; u++) {
        const int r = wv + 4*u;
        const float* xr = X + (size_t)(row0 + r) * HIDDEN;
#pragma unroll
        for (int q = 0; q < 4; q++) {
            const int p = q*256 + 4*lane;
            const float4 v = *reinterpret_cast<const float4*>(xr + p);
            *reinterpret_cast<float4*>(lds + r*RSTR + (p >> 5)*BSTR + (p & 31)) = v;
        }
    }

    // ---------- gamma/beta loads hoisted BEFORE the cast-chunk issue ----------
    // (older vmem ops complete in-order, so phase C's g4/b4 consumption never
    //  waits behind the younger cast loads)
    float4 g4[4], b4[4];
#pragma unroll
    for (int q = 0; q < 4; q++) {
        g4[q] = *reinterpret_cast<const float4*>(G  + q*256 + 4*lane);
        b4[q] = *reinterpret_cast<const float4*>(Bt + q*256 + 4*lane);
    }

    // ---------- cast pipeline: issue chunk 0 (k = 0..3) ----------
    // 4 chunks x 4 k-iters cover the original 16-iteration cast loop.
    // Each chunk: 8x float4 loads held in VGPRs, converted+stored after the
    // NEXT stage's einsum (>= one full stage of VALU work in between).
    const float* csrc = TBL   + (size_t)blockIdx.x * 32768;
    __half*      cdst = TBL16 + (size_t)blockIdx.x * 32768;
    float4 ca[8];
    if constexpr (SPLIT) {
#pragma unroll
        for (int j = 0; j < 4; j++) {
            const int idx = (j*256 + t) * 8;
            ca[2*j]   = *reinterpret_cast<const float4*>(csrc + idx);
            ca[2*j+1] = *reinterpret_cast<const float4*>(csrc + idx + 4);
        }
    }

    // ---------- Phase B: numpy-pairwise mean/var (bit-exact np.mean order) ----------
    float mu0, mu4, rs0, rs4;
    {
        float bsum = 0.f;
        if (lane < 16) {
            const int row = wv + 4*(lane >> 3);
            const int blk = lane & 7;
            const float* bp = lds + row*RSTR + blk*4*BSTR;
            float r8[8];
            {
                const float4 f0 = *reinterpret_cast<const float4*>(bp);
                const float4 f1 = *reinterpret_cast<const float4*>(bp + 4);
                r8[0]=f0.x; r8[1]=f0.y; r8[2]=f0.z; r8[3]=f0.w;
                r8[4]=f1.x; r8[5]=f1.y; r8[6]=f1.z; r8[7]=f1.w;
            }
#pragma unroll
            for (int m = 1; m < 16; m++) {
                const int p = 8*m;
                const float* qp = bp + (p >> 5)*BSTR + (p & 31);
                const float4 f0 = *reinterpret_cast<const float4*>(qp);
                const float4 f1 = *reinterpret_cast<const float4*>(qp + 4);
                r8[0]=__fadd_rn(r8[0],f0.x); r8[1]=__fadd_rn(r8[1],f0.y);
                r8[2]=__fadd_rn(r8[2],f0.z); r8[3]=__fadd_rn(r8[3],f0.w);
                r8[4]=__fadd_rn(r8[4],f1.x); r8[5]=__fadd_rn(r8[5],f1.y);
                r8[6]=__fadd_rn(r8[6],f1.z); r8[7]=__fadd_rn(r8[7],f1.w);
            }
            bsum = __fadd_rn(__fadd_rn(__fadd_rn(r8[0],r8[1]), __fadd_rn(r8[2],r8[3])),
                             __fadd_rn(__fadd_rn(r8[4],r8[5]), __fadd_rn(r8[6],r8[7])));
        }
        float v = bsum;
        v = __fadd_rn(v, __shfl_xor(v, 1, 64));
        v = __fadd_rn(v, __shfl_xor(v, 2, 64));
        v = __fadd_rn(v, __shfl_xor(v, 4, 64));
        mu0 = __fmul_rn(__shfl(v, 0, 64), 0.0009765625f);
        mu4 = __fmul_rn(__shfl(v, 8, 64), 0.0009765625f);

        float bss = 0.f;
        if (lane < 16) {
            const int row = wv + 4*(lane >> 3);
            const float mu = (lane & 8) ? mu4 : mu0;
            const int blk = lane & 7;
            const float* bp = lds + row*RSTR + blk*4*BSTR;
            float r8[8];
            {
                const float4 f0 = *reinterpret_cast<const float4*>(bp);
                const float4 f1 = *reinterpret_cast<const float4*>(bp + 4);
                float d;
                d=__fsub_rn(f0.x,mu); r8[0]=__fmul_rn(d,d);
                d=__fsub_rn(f0.y,mu); r8[1]=__fmul_rn(d,d);
                d=__fsub_rn(f0.z,mu); r8[2]=__fmul_rn(d,d);
                d=__fsub_rn(f0.w,mu); r8[3]=__fmul_rn(d,d);
                d=__fsub_rn(f1.x,mu); r8[4]=__fmul_rn(d,d);
                d=__fsub_rn(f1.y,mu); r8[5]=__fmul_rn(d,d);
                d=__fsub_rn(f1.z,mu); r8[6]=__fmul_rn(d,d);
                d=__fsub_rn(f1.w,mu); r8[7]=__fmul_rn(d,d);
            }
#pragma unroll
            for (int m = 1; m < 16; m++) {
                const int p = 8*m;
                const float* qp = bp + (p >> 5)*BSTR + (p & 31);
                const float4 f0 = *reinterpret_cast<const float4*>(qp);
                const float4 f1 = *reinterpret_cast<const float4*>(qp + 4);
                float d;
                d=__fsub_rn(f0.x,mu); r8[0]=__fadd_rn(r8[0],__fmul_rn(d,d));
                d=__fsub_rn(f0.y,mu); r8[1]=__fadd_rn(r8[1],__fmul_rn(d,d));
                d=__fsub_rn(f0.z,mu); r8[2]=__fadd_rn(r8[2],__fmul_rn(d,d));
                d=__fsub_rn(f0.w,mu); r8[3]=__fadd_rn(r8[3],__fmul_rn(d,d));
                d=__fsub_rn(f1.x,mu); r8[4]=__fadd_rn(r8[4],__fmul_rn(d,d));
                d=__fsub_rn(f1.y,mu); r8[5]=__fadd_rn(r8[5],__fmul_rn(d,d));
                d=__fsub_rn(f1.z,mu); r8[6]=__fadd_rn(r8[6],__fmul_rn(d,d));
                d=__fsub_rn(f1.w,mu); r8[7]=__fadd_rn(r8[7],__fmul_rn(d,d));
            }
            bss = __fadd_rn(__fadd_rn(__fadd_rn(r8[0],r8[1]), __fadd_rn(r8[2],r8[3])),
                            __fadd_rn(__fadd_rn(r8[4],r8[5]), __fadd_rn(r8[6],r8[7])));
        }
        float v2 = bss;
        v2 = __fadd_rn(v2, __shfl_xor(v2, 1, 64));
        v2 = __fadd_rn(v2, __shfl_xor(v2, 2, 64));
        v2 = __fadd_rn(v2, __shfl_xor(v2, 4, 64));
        const float var0 = __fmul_rn(__shfl(v2, 0, 64), 0.0009765625f);
        const float var4 = __fmul_rn(__shfl(v2, 8, 64), 0.0009765625f);
        rs0 = __fdiv_rn(1.0f, __fsqrt_rn(__fadd_rn(var0, 1e-12f)));
        rs4 = __fdiv_rn(1.0f, __fsqrt_rn(__fadd_rn(var4, 1e-12f)));
    }

    // ---------- Phase C: xn = ((x-mu)*rstd)*gamma + beta, in place ----------
    float4 xn0[2], xn1[2];
    {
#pragma unroll
        for (int u = 0; u < 2; u++) {
            const int r = wv + 4*u;
            const float mu = u ? mu4 : mu0;
            const float rstd = u ? rs4 : rs0;
#pragma unroll
            for (int q = 0; q < 4; q++) {
                const int p = q*256 + 4*lane;
                float* ptr = lds + r*RSTR + (p >> 5)*BSTR + (p & 31);
                const float4 x4 = *reinterpret_cast<float4*>(ptr);
                float4 xn;
                xn.x = __fadd_rn(__fmul_rn(__fmul_rn(__fsub_rn(x4.x, mu), rstd), g4[q].x), b4[q].x);
                xn.y = __fadd_rn(__fmul_rn(__fmul_rn(__fsub_rn(x4.y, mu), rstd), g4[q].y), b4[q].y);
                xn.z = __fadd_rn(__fmul_rn(__fmul_rn(__fsub_rn(x4.z, mu), rstd), g4[q].z), b4[q].z);
                xn.w = __fadd_rn(__fmul_rn(__fmul_rn(__fsub_rn(x4.w, mu), rstd), g4[q].w), b4[q].w);
                *reinterpret_cast<float4*>(ptr) = xn;
                if (q == 0) xn0[u] = xn;
                if (q == 1) xn1[u] = xn;
            }
        }
    }
    __syncthreads();

    // ---------- Phase D: 4 BH4 stages, np-einsum order + ascending FWHT ----------
    const int Bm = t >> 3;
    const int j0 = (t & 7) * 4;
#pragma unroll 1
    for (int s = 0; s < 4; s++) {
        float acc[RPB][4];
#pragma unroll
        for (int r = 0; r < RPB; r++)
#pragma unroll
            for (int c = 0; c < 4; c++) acc[r][c] = 0.0f;
        const float* Wb = W + s*32768 + Bm*1024 + j0;
#pragma unroll 2
        for (int iq = 0; iq < 8; iq++) {
            const float4 w0 = *reinterpret_cast<const float4*>(Wb + (iq*4 + 0)*32);
            const float4 w1 = *reinterpret_cast<const float4*>(Wb + (iq*4 + 1)*32);
            const float4 w2 = *reinterpret_cast<const float4*>(Wb + (iq*4 + 2)*32);
            const float4 w3 = *reinterpret_cast<const float4*>(Wb + (iq*4 + 3)*32);
#pragma unroll
            for (int r = 0; r < RPB; r++) {
                const float4 h4 = *reinterpret_cast<const float4*>(lds + r*RSTR + Bm*BSTR + iq*4);
                acc[r][0]=__fadd_rn(acc[r][0],__fmul_rn(h4.x,w0.x));
                acc[r][0]=__fadd_rn(acc[r][0],__fmul_rn(h4.y,w1.x));
                acc[r][0]=__fadd_rn(acc[r][0],__fmul_rn(h4.z,w2.x));
                acc[r][0]=__fadd_rn(acc[r][0],__fmul_rn(h4.w,w3.x));
                acc[r][1]=__fadd_rn(acc[r][1],__fmul_rn(h4.x,w0.y));
                acc[r][1]=__fadd_rn(acc[r][1],__fmul_rn(h4.y,w1.y));
                acc[r][1]=__fadd_rn(acc[r][1],__fmul_rn(h4.z,w2.y));
                acc[r][1]=__fadd_rn(acc[r][1],__fmul_rn(h4.w,w3.y));
                acc[r][2]=__fadd_rn(acc[r][2],__fmul_rn(h4.x,w0.z));
                acc[r][2]=__fadd_rn(acc[r][2],__fmul_rn(h4.y,w1.z));
                acc[r][2]=__fadd_rn(acc[r][2],__fmul_rn(h4.z,w2.z));
                acc[r][2]=__fadd_rn(acc[r][2],__fmul_rn(h4.w,w3.z));
                acc[r][3]=__fadd_rn(acc[r][3],__fmul_rn(h4.x,w0.w));
                acc[r][3]=__fadd_rn(acc[r][3],__fmul_rn(h4.y,w1.w));
                acc[r][3]=__fadd_rn(acc[r][3],__fmul_rn(h4.z,w2.w));
                acc[r][3]=__fadd_rn(acc[r][3],__fmul_rn(h4.w,w3.w));
            }
        }
        // NOTE: no __syncthreads() here. Readers and writers of each 32-word
        // LDS block Bm are the same aligned 8-thread group (t>>3 == Bm) inside
        // one wave; per-wave in-order LDS ops make the barrier redundant.

        // ---- cast pipeline: flush chunk s (issued >= 1 stage ago), issue s+1 ----
        if constexpr (SPLIT) {
#pragma unroll
            for (int j = 0; j < 4; j++) {
                const int k = s*4 + j;
                const int idx = (k*256 + t) * 8;
                union { uint4 u4; __half2 h2[4]; } pk;
                pk.h2[0] = __floats2half2_rn(ca[2*j].x,   ca[2*j].y);
                pk.h2[1] = __floats2half2_rn(ca[2*j].z,   ca[2*j].w);
                pk.h2[2] = __floats2half2_rn(ca[2*j+1].x, ca[2*j+1].y);
                pk.h2[3] = __floats2half2_rn(ca[2*j+1].z, ca[2*j+1].w);
                *reinterpret_cast<uint4*>(cdst + idx) = pk.u4;
            }
            if (s < 3) {
#pragma unroll
                for (int j = 0; j < 4; j++) {
                    const int k = (s+1)*4 + j;
                    const int idx = (k*256 + t) * 8;
                    ca[2*j]   = *reinterpret_cast<const float4*>(csrc + idx);
                    ca[2*j+1] = *reinterpret_cast<const float4*>(csrc + idx + 4);
                }
            }
        }

#pragma unroll
        for (int r = 0; r < RPB; r++) {
            const float a = acc[r][0], b = acc[r][1], c = acc[r][2], d = acc[r][3];
            const float s0 = __fadd_rn(a,b), d0 = __fsub_rn(a,b);
            const float s1 = __fadd_rn(c,d), d1 = __fsub_rn(c,d);
            *reinterpret_cast<float4*>(lds + r*RSTR + Bm*BSTR + j0) =
                f4(__fadd_rn(s0,s1), __fadd_rn(d0,d1), __fsub_rn(s0,s1), __fsub_rn(d0,d1));
        }
        __syncthreads();

        {
            const int rr = t >> 5, bb = t & 31;
            float* bp = lds + rr*RSTR + bb*BSTR;
            float4 v[8];
#pragma unroll
            for (int k = 0; k < 8; k++) v[k] = *reinterpret_cast<float4*>(bp + 4*k);
#pragma unroll
            for (int m = 1; m < 8; m <<= 1) {
#pragma unroll
                for (int k = 0; k < 8; k++) if (!(k & m)) {
                    const float4 a = v[k], b = v[k | m];
                    v[k]     = f4(__fadd_rn(a.x,b.x), __fadd_rn(a.y,b.y),
                                  __fadd_rn(a.z,b.z), __fadd_rn(a.w,b.w));
                    v[k | m] = f4(__fsub_rn(a.x,b.x), __fsub_rn(a.y,b.y),
                                  __fsub_rn(a.z,b.z), __fsub_rn(a.w,b.w));
                }
            }
#pragma unroll
            for (int k = 0; k < 8; k++) *reinterpret_cast<float4*>(bp + 4*k) = v[k];
        }
        __syncthreads();

        {
            const int rr = t >> 5, J = t & 31;
            float* bp = lds + rr*RSTR + J;
            float g[32];
#pragma unroll
            for (int k = 0; k < 32; k++) g[k] = bp[k*BSTR];
#pragma unroll
            for (int m = 1; m < 32; m <<= 1) {
#pragma unroll
                for (int k = 0; k < 32; k++) if (!(k & m)) {
                    const float a = g[k], b = g[k | m];
                    g[k] = __fadd_rn(a,b); g[k | m] = __fsub_rn(a,b);
                }
            }
#pragma unroll
            for (int k = 0; k < 32; k++) bp[k*BSTR] = g[k];
        }
        __syncthreads();
    }

    // ---------- Phase E: z = (0.7*h) + (0.3*xn) + bias, p < 320 ----------
    {
        const float c0 = 0.7f, c1 = 0.3f;
#pragma unroll
        for (int u = 0; u < 2; u++) {
            const int r = wv + 4*u;
            {
                const int p = 4*lane;
                const float4 zb = *reinterpret_cast<const float4*>(ZB + p);
                float* zp = lds + r*RSTR + (p >> 5)*BSTR + (p & 31);
                float4 h4 = *reinterpret_cast<float4*>(zp);
                h4.x = __fadd_rn(__fadd_rn(__fmul_rn(c0,h4.x), __fmul_rn(c1,xn0[u].x)), zb.x);
                h4.y = __fadd_rn(__fadd_rn(__fmul_rn(c0,h4.y), __fmul_rn(c1,xn0[u].y)), zb.y);
                h4.z = __fadd_rn(__fadd_rn(__fmul_rn(c0,h4.z), __fmul_rn(c1,xn0[u].z)), zb.z);
                h4.w = __fadd_rn(__fadd_rn(__fmul_rn(c0,h4.w), __fmul_rn(c1,xn0[u].w)), zb.w);
                *reinterpret_cast<float4*>(zp) = h4;
            }
            if (lane < 16) {
                const int p = 256 + 4*lane;
                const float4 zb = *reinterpret_cast<const float4*>(ZB + p);
                float* zp = lds + r*RSTR + (p >> 5)*BSTR + (p & 31);
                float4 h4 = *reinterpret_cast<float4*>(zp);
                h4.x = __fadd_rn(__fadd_rn(__fmul_rn(c0,h4.x), __fmul_rn(c1,xn1[u].x)), zb.x);
                h4.y = __fadd_rn(__fadd_rn(__fmul_rn(c0,h4.y), __fmul_rn(c1,xn1[u].y)), zb.y);
                h4.z = __fadd_rn(__fadd_rn(__fmul_rn(c0,h4.z), __fmul_rn(c1,xn1[u].z)), zb.z);
                h4.w = __fadd_rn(__fadd_rn(__fmul_rn(c0,h4.w), __fmul_rn(c1,xn1[u].w)), zb.w);
                *reinterpret_cast<float4*>(zp) = h4;
            }
        }
    }
    __syncthreads();

    // ---------- Phase F: codes & scores ----------
    {
        const int r = t >> 5, T = t & 31;
        int code = 0; float sc = 1.f;
#pragma unroll
        for (int d = 0; d < CODE_LEN; d++) {
            const int p = T*CODE_LEN + d;
            const float z = lds[r*RSTR + (p >> 5)*BSTR + (p & 31)];
            if (z > 0.f) code |= (1 << d);
            sc *= 1.f / (1.f + expf(-fabsf(z)));
        }
        if constexpr (SPLIT) {
            SC[(size_t)row0 * NUM_TABLE + t] = sc;
            CD[(size_t)row0 * NUM_TABLE + t] = code;
        } else {
            l_sc[t] = sc;
            l_cd[t] = code;
        }
    }

    // ---------- Fallback-only: fp32 gather in-kernel (proven R3 path) ----------
    if constexpr (!SPLIT) {
        __syncthreads();
        float4 ob[4];
#pragma unroll
        for (int q = 0; q < 4; q++)
            ob[q] = *reinterpret_cast<const float4*>(OB + q*256 + 4*lane);
#pragma unroll
        for (int u = 0; u < 2; u++) {
            const int r = wv + 4*u;
            float4 o[4];
#pragma unroll
            for (int q = 0; q < 4; q++) o[q] = ob[q];
#pragma unroll 4
            for (int T = 0; T < NUM_TABLE; T++) {
                const float sc  = l_sc[r*NUM_TABLE + T];
                const int code  = l_cd[r*NUM_TABLE + T];
                const float* tbf = TBL + ((size_t)(T*1024 + code)) * 1024;
#pragma unroll
                for (int q = 0; q < 4; q++) {
                    const float4 tv = *reinterpret_cast<const float4*>(tbf + q*256 + 4*lane);
                    o[q].x += sc * tv.x; o[q].y += sc * tv.y;
                    o[q].z += sc * tv.z; o[q].w += sc * tv.w;
                }
            }
            float* orow = OUT + (size_t)(row0 + r) * HIDDEN;
#pragma unroll
            for (int q = 0; q < 4; q++)
                *reinterpret_cast<float4*>(orow + q*256 + 4*lane) = o[q];
        }
    }
}

// ============================================================================
// K2: fp16 gather. One wave per row; lane owns halves [lane*8..+7] and
// [512+lane*8..+7]. Double-buffered 4-table groups: group g+1's 8x16B loads
// are issued before group g is consumed (fully unrolled -> static buffer
// indices, no scratch), so each wave always has ~16 loads in flight.
// ============================================================================
__global__ __launch_bounds__(256, 4) void gather_kernel(
    const __half* __restrict__ TBL16,
    const float* __restrict__ SC,
    const int*   __restrict__ CD,
    const float* __restrict__ OB,
    float* __restrict__ OUT)
{
    __shared__ float s_sc[4 * NUM_TABLE];
    __shared__ int   s_cd[4 * NUM_TABLE];
    const int t = threadIdx.x, lane = t & 63, wv = t >> 6;
    const int row0 = blockIdx.x * 4;

    if (t < 128) {
        s_sc[t] = SC[(size_t)row0 * NUM_TABLE + t];
        s_cd[t] = CD[(size_t)row0 * NUM_TABLE + t];
    }
    __syncthreads();

    float4 o[4];
    o[0] = *reinterpret_cast<const float4*>(OB + lane*8);
    o[1] = *reinterpret_cast<const float4*>(OB + lane*8 + 4);
    o[2] = *reinterpret_cast<const float4*>(OB + 512 + lane*8);
    o[3] = *reinterpret_cast<const float4*>(OB + 512 + lane*8 + 4);

    uint4 va[2][4][2];
    float sc[2][4];

    // prefetch group 0 (tables 0..3)
#pragma unroll
    for (int k = 0; k < 4; k++) {
        sc[0][k] = s_sc[wv*NUM_TABLE + k];
        const int code = s_cd[wv*NUM_TABLE + k];
        const __half* tb = TBL16 + (((size_t)(k*1024 + code)) << 10);
        va[0][k][0] = *reinterpret_cast<const uint4*>(tb + lane*8);
        va[0][k][1] = *reinterpret_cast<const uint4*>(tb + 512 + lane*8);
    }

#pragma unroll
    for (int g = 0; g < 8; g++) {
        const int cb = g & 1, nb = cb ^ 1;
        if (g < 7) {
#pragma unroll
            for (int k = 0; k < 4; k++) {
                const int T = (g+1)*4 + k;
                sc[nb][k] = s_sc[wv*NUM_TABLE + T];
                const int code = s_cd[wv*NUM_TABLE + T];
                const __half* tb = TBL16 + (((size_t)(T*1024 + code)) << 10);
                va[nb][k][0] = *reinterpret_cast<const uint4*>(tb + lane*8);
                va[nb][k][1] = *reinterpret_cast<const uint4*>(tb + 512 + lane*8);
            }
        }
#pragma unroll
        for (int k = 0; k < 4; k++) {
            const __half2* h0 = reinterpret_cast<const __half2*>(&va[cb][k][0]);
            const __half2* h1 = reinterpret_cast<const __half2*>(&va[cb][k][1]);
            const float s = sc[cb][k];
            float2 f;
            f = __half22float2(h0[0]); o[0].x += s*f.x; o[0].y += s*f.y;
            f = __half22float2(h0[1]); o[0].z += s*f.x; o[0].w += s*f.y;
            f = __half22float2(h0[2]); o[1].x += s*f.x; o[1].y += s*f.y;
            f = __half22float2(h0[3]); o[1].z += s*f.x; o[1].w += s*f.y;
            f = __half22float2(h1[0]); o[2].x += s*f.x; o[2].y += s*f.y;
            f = __half22float2(h1[1]); o[2].z += s*f.x; o[2].w += s*f.y;
            f = __half22float2(h1[2]); o[3].x += s*f.x; o[3].y += s*f.y;
            f = __half22float2(h1[3]); o[3].z += s*f.x; o[3].w += s*f.y;
        }
    }

    float* orow = OUT + (size_t)(row0 + wv) * HIDDEN;
    *reinterpret_cast<float4*>(orow + lane*8)           = o[0];
    *reinterpret_cast<float4*>(orow + lane*8 + 4)       = o[1];
    *reinterpret_cast<float4*>(orow + 512 + lane*8)     = o[2];
    *reinterpret_cast<float4*>(orow + 512 + lane*8 + 4) = o[3];
}

extern "C" void kernel_launch(void* const* d_in, const int* in_sizes, int n_in,
                              void* d_out, int out_size, void* d_ws, size_t ws_size,
                              hipStream_t stream) {
    const float* X   = (const float*)d_in[0];
    const float* G   = (const float*)d_in[1];
    const float* Bt  = (const float*)d_in[2];
    const float* W   = (const float*)d_in[3];
    const float* ZB  = (const float*)d_in[4];
    const float* TBL = (const float*)d_in[5];
    const float* OB  = (const float*)d_in[6];
    float* OUT = (float*)d_out;

    const int rows = in_sizes[0] / HIDDEN;     // 8192
    const int grid = rows / RPB;               // 1024 blocks

    // ws layout: [tables fp16: 64 MiB][scores: rows*32 f32][codes: rows*32 i32]
    const size_t tbl_bytes = (size_t)TBL_ELEMS * sizeof(__half);
    const size_t sc_bytes  = (size_t)rows * NUM_TABLE * sizeof(float);
    const size_t need = tbl_bytes + 2 * sc_bytes;
    __half* TBL16 = (__half*)d_ws;
    float*  SC    = (float*)((char*)d_ws + tbl_bytes);
    int*    CD    = (int*)((char*)d_ws + tbl_bytes + sc_bytes);

    if (ws_size >= need && grid == 1024) {
        hipLaunchKernelGGL(compute_kernel<true>, dim3(grid), dim3(256), 0, stream,
                           X, G, Bt, W, ZB, TBL, OB, OUT, TBL16, SC, CD);
        hipLaunchKernelGGL(gather_kernel, dim3(rows / 4), dim3(256), 0, stream,
                           TBL16, SC, CD, OB, OUT);
    } else {
        // proven R3 monolithic fp32 path
        hipLaunchKernelGGL(compute_kernel<false>, dim3(grid), dim3(256), 0, stream,
                           X, G, Bt, W, ZB, TBL, OB, OUT, TBL16, SC, CD);
    }
}

// Round 2
// 346.614 us; speedup vs baseline: 1.4037x; 1.4037x over previous
//
#include <hip/hip_runtime.h>
#include <hip/hip_fp16.h>
#include <math.h>

#define HIDDEN 1024
#define CODE_LEN 10
#define NUM_TABLE 32
#define RPB 8            // rows per block (K1)
#define BSTR 36          // padded words per 32-elem block in LDS
#define RSTR (32*BSTR)   // 1152 words per row
#define TBL_ELEMS (32u*1024u*1024u)   // 33,554,432

__device__ __forceinline__ float4 f4(float a, float b, float c, float d) {
    return make_float4(a, b, c, d);
}

// ============================================================================
// K1: cast tables fp32->fp16 (phase 0) + bit-exact LN/BH4/codes -> SC/CD in ws
// (round-0 proven structure: 128 us, VGPR 56). Only change vs round-0: the
// post-einsum __syncthreads() is removed — readers and writers of each
// 32-word LDS block Bm are the same aligned 8-thread group (t>>3 == Bm)
// within one wave, and same-wave DS ops are processed in issue order.
// CAST=false variant used by the monolithic fallback path.
// ============================================================================
template <bool SPLIT>
__global__ __launch_bounds__(256, 4) void compute_kernel(
    const float* __restrict__ X,   // [rows,1024]
    const float* __restrict__ G,   // [1024] ln_gamma
    const float* __restrict__ Bt,  // [1024] ln_beta
    const float* __restrict__ W,   // [1,4,32,32,32] bh4_weight
    const float* __restrict__ ZB,  // [320] bh4_bias
    const float* __restrict__ TBL, // [32*1024,1024] tables flat (fp32)
    const float* __restrict__ OB,  // [1024] out_bias
    float* __restrict__ OUT,       // [rows,1024]
    __half* __restrict__ TBL16,    // ws: fp16 tables
    float* __restrict__ SC,        // ws: [rows*32] scores
    int*   __restrict__ CD)        // ws: [rows*32] codes
{
    __shared__ float lds[RPB * RSTR];          // 36864 B
    __shared__ float l_sc[RPB * NUM_TABLE];    // only used by !SPLIT path
    __shared__ int   l_cd[RPB * NUM_TABLE];

    const int t    = threadIdx.x;
    const int lane = t & 63;
    const int wv   = t >> 6;
    const int row0 = blockIdx.x * RPB;

    // ---------- Phase 0 (SPLIT only): cast this block's table slice fp32->fp16 ----------
    if constexpr (SPLIT) {
        const float* src = TBL   + (size_t)blockIdx.x * 32768;
        __half*      dst = TBL16 + (size_t)blockIdx.x * 32768;
#pragma unroll
        for (int k = 0; k < 16; k++) {
            const int idx = (k*256 + t) * 8;
            const float4 a = *reinterpret_cast<const float4*>(src + idx);
            const float4 b = *reinterpret_cast<const float4*>(src + idx + 4);
            union { uint4 u4; __half2 h2[4]; } pk;
            pk.h2[0] = __floats2half2_rn(a.x, a.y);
            pk.h2[1] = __floats2half2_rn(a.z, a.w);
            pk.h2[2] = __floats2half2_rn(b.x, b.y);
            pk.h2[3] = __floats2half2_rn(b.z, b.w);
            *reinterpret_cast<uint4*>(dst + idx) = pk.u4;
        }
    }

    // ---------- Phase A: load raw x into padded LDS ----------
#pragma unroll
    for (int u = 0; u < 2; u++) {
        const int r = wv + 4*u;
        const float* xr = X + (size_t)(row0 + r) * HIDDEN;
#pragma unroll
        for (int q = 0; q < 4; q++) {
            const int p = q*256 + 4*lane;
            const float4 v = *reinterpret_cast<const float4*>(xr + p);
            *reinterpret_cast<float4*>(lds + r*RSTR + (p >> 5)*BSTR + (p & 31)) = v;
        }
    }

    // ---------- Phase B: numpy-pairwise mean/var (bit-exact np.mean order) ----------
    float mu0, mu4, rs0, rs4;
    {
        float bsum = 0.f;
        if (lane < 16) {
            const int row = wv + 4*(lane >> 3);
            const int blk = lane & 7;
            const float* bp = lds + row*RSTR + blk*4*BSTR;
            float r8[8];
            {
                const float4 f0 = *reinterpret_cast<const float4*>(bp);
                const float4 f1 = *reinterpret_cast<const float4*>(bp + 4);
                r8[0]=f0.x; r8[1]=f0.y; r8[2]=f0.z; r8[3]=f0.w;
                r8[4]=f1.x; r8[5]=f1.y; r8[6]=f1.z; r8[7]=f1.w;
            }
#pragma unroll
            for (int m = 1; m < 16; m++) {
                const int p = 8*m;
                const float* qp = bp + (p >> 5)*BSTR + (p & 31);
                const float4 f0 = *reinterpret_cast<const float4*>(qp);
                const float4 f1 = *reinterpret_cast<const float4*>(qp + 4);
                r8[0]=__fadd_rn(r8[0],f0.x); r8[1]=__fadd_rn(r8[1],f0.y);
                r8[2]=__fadd_rn(r8[2],f0.z); r8[3]=__fadd_rn(r8[3],f0.w);
                r8[4]=__fadd_rn(r8[4],f1.x); r8[5]=__fadd_rn(r8[5],f1.y);
                r8[6]=__fadd_rn(r8[6],f1.z); r8[7]=__fadd_rn(r8[7],f1.w);
            }
            bsum = __fadd_rn(__fadd_rn(__fadd_rn(r8[0],r8[1]), __fadd_rn(r8[2],r8[3])),
                             __fadd_rn(__fadd_rn(r8[4],r8[5]), __fadd_rn(r8[6],r8[7])));
        }
        float v = bsum;
        v = __fadd_rn(v, __shfl_xor(v, 1, 64));
        v = __fadd_rn(v, __shfl_xor(v, 2, 64));
        v = __fadd_rn(v, __shfl_xor(v, 4, 64));
        mu0 = __fmul_rn(__shfl(v, 0, 64), 0.0009765625f);
        mu4 = __fmul_rn(__shfl(v, 8, 64), 0.0009765625f);

        float bss = 0.f;
        if (lane < 16) {
            const int row = wv + 4*(lane >> 3);
            const float mu = (lane & 8) ? mu4 : mu0;
            const int blk = lane & 7;
            const float* bp = lds + row*RSTR + blk*4*BSTR;
            float r8[8];
            {
                const float4 f0 = *reinterpret_cast<const float4*>(bp);
                const float4 f1 = *reinterpret_cast<const float4*>(bp + 4);
                float d;
                d=__fsub_rn(f0.x,mu); r8[0]=__fmul_rn(d,d);
                d=__fsub_rn(f0.y,mu); r8[1]=__fmul_rn(d,d);
                d=__fsub_rn(f0.z,mu); r8[2]=__fmul_rn(d,d);
                d=__fsub_rn(f0.w,mu); r8[3]=__fmul_rn(d,d);
                d=__fsub_rn(f1.x,mu); r8[4]=__fmul_rn(d,d);
                d=__fsub_rn(f1.y,mu); r8[5]=__fmul_rn(d,d);
                d=__fsub_rn(f1.z,mu); r8[6]=__fmul_rn(d,d);
                d=__fsub_rn(f1.w,mu); r8[7]=__fmul_rn(d,d);
            }
#pragma unroll
            for (int m = 1; m < 16; m++) {
                const int p = 8*m;
                const float* qp = bp + (p >> 5)*BSTR + (p & 31);
                const float4 f0 = *reinterpret_cast<const float4*>(qp);
                const float4 f1 = *reinterpret_cast<const float4*>(qp + 4);
                float d;
                d=__fsub_rn(f0.x,mu); r8[0]=__fadd_rn(r8[0],__fmul_rn(d,d));
                d=__fsub_rn(f0.y,mu); r8[1]=__fadd_rn(r8[1],__fmul_rn(d,d));
                d=__fsub_rn(f0.z,mu); r8[2]=__fadd_rn(r8[2],__fmul_rn(d,d));
                d=__fsub_rn(f0.w,mu); r8[3]=__fadd_rn(r8[3],__fmul_rn(d,d));
                d=__fsub_rn(f1.x,mu); r8[4]=__fadd_rn(r8[4],__fmul_rn(d,d));
                d=__fsub_rn(f1.y,mu); r8[5]=__fadd_rn(r8[5],__fmul_rn(d,d));
                d=__fsub_rn(f1.z,mu); r8[6]=__fadd_rn(r8[6],__fmul_rn(d,d));
                d=__fsub_rn(f1.w,mu); r8[7]=__fadd_rn(r8[7],__fmul_rn(d,d));
            }
            bss = __fadd_rn(__fadd_rn(__fadd_rn(r8[0],r8[1]), __fadd_rn(r8[2],r8[3])),
                            __fadd_rn(__fadd_rn(r8[4],r8[5]), __fadd_rn(r8[6],r8[7])));
        }
        float v2 = bss;
        v2 = __fadd_rn(v2, __shfl_xor(v2, 1, 64));
        v2 = __fadd_rn(v2, __shfl_xor(v2, 2, 64));
        v2 = __fadd_rn(v2, __shfl_xor(v2, 4, 64));
        const float var0 = __fmul_rn(__shfl(v2, 0, 64), 0.0009765625f);
        const float var4 = __fmul_rn(__shfl(v2, 8, 64), 0.0009765625f);
        rs0 = __fdiv_rn(1.0f, __fsqrt_rn(__fadd_rn(var0, 1e-12f)));
        rs4 = __fdiv_rn(1.0f, __fsqrt_rn(__fadd_rn(var4, 1e-12f)));
    }

    // ---------- Phase C: xn = ((x-mu)*rstd)*gamma + beta, in place ----------
    float4 xn0[2], xn1[2];
    {
        float4 g4[4], b4[4];
#pragma unroll
        for (int q = 0; q < 4; q++) {
            g4[q] = *reinterpret_cast<const float4*>(G  + q*256 + 4*lane);
            b4[q] = *reinterpret_cast<const float4*>(Bt + q*256 + 4*lane);
        }
#pragma unroll
        for (int u = 0; u < 2; u++) {
            const int r = wv + 4*u;
            const float mu = u ? mu4 : mu0;
            const float rstd = u ? rs4 : rs0;
#pragma unroll
            for (int q = 0; q < 4; q++) {
                const int p = q*256 + 4*lane;
                float* ptr = lds + r*RSTR + (p >> 5)*BSTR + (p & 31);
                const float4 x4 = *reinterpret_cast<float4*>(ptr);
                float4 xn;
                xn.x = __fadd_rn(__fmul_rn(__fmul_rn(__fsub_rn(x4.x, mu), rstd), g4[q].x), b4[q].x);
                xn.y = __fadd_rn(__fmul_rn(__fmul_rn(__fsub_rn(x4.y, mu), rstd), g4[q].y), b4[q].y);
                xn.z = __fadd_rn(__fmul_rn(__fmul_rn(__fsub_rn(x4.z, mu), rstd), g4[q].z), b4[q].z);
                xn.w = __fadd_rn(__fmul_rn(__fmul_rn(__fsub_rn(x4.w, mu), rstd), g4[q].w), b4[q].w);
                *reinterpret_cast<float4*>(ptr) = xn;
                if (q == 0) xn0[u] = xn;
                if (q == 1) xn1[u] = xn;
            }
        }
    }
    __syncthreads();

    // ---------- Phase D: 4 BH4 stages, np-einsum order + ascending FWHT ----------
    const int Bm = t >> 3;
    const int j0 = (t & 7) * 4;
#pragma unroll 1
    for (int s = 0; s < 4; s++) {
        float acc[RPB][4];
#pragma unroll
        for (int r = 0; r < RPB; r++)
#pragma unroll
            for (int c = 0; c < 4; c++) acc[r][c] = 0.0f;
        const float* Wb = W + s*32768 + Bm*1024 + j0;
#pragma unroll 2
        for (int iq = 0; iq < 8; iq++) {
            const float4 w0 = *reinterpret_cast<const float4*>(Wb + (iq*4 + 0)*32);
            const float4 w1 = *reinterpret_cast<const float4*>(Wb + (iq*4 + 1)*32);
            const float4 w2 = *reinterpret_cast<const float4*>(Wb + (iq*4 + 2)*32);
            const float4 w3 = *reinterpret_cast<const float4*>(Wb + (iq*4 + 3)*32);
#pragma unroll
            for (int r = 0; r < RPB; r++) {
                const float4 h4 = *reinterpret_cast<const float4*>(lds + r*RSTR + Bm*BSTR + iq*4);
                acc[r][0]=__fadd_rn(acc[r][0],__fmul_rn(h4.x,w0.x));
                acc[r][0]=__fadd_rn(acc[r][0],__fmul_rn(h4.y,w1.x));
                acc[r][0]=__fadd_rn(acc[r][0],__fmul_rn(h4.z,w2.x));
                acc[r][0]=__fadd_rn(acc[r][0],__fmul_rn(h4.w,w3.x));
                acc[r][1]=__fadd_rn(acc[r][1],__fmul_rn(h4.x,w0.y));
                acc[r][1]=__fadd_rn(acc[r][1],__fmul_rn(h4.y,w1.y));
                acc[r][1]=__fadd_rn(acc[r][1],__fmul_rn(h4.z,w2.y));
                acc[r][1]=__fadd_rn(acc[r][1],__fmul_rn(h4.w,w3.y));
                acc[r][2]=__fadd_rn(acc[r][2],__fmul_rn(h4.x,w0.z));
                acc[r][2]=__fadd_rn(acc[r][2],__fmul_rn(h4.y,w1.z));
                acc[r][2]=__fadd_rn(acc[r][2],__fmul_rn(h4.z,w2.z));
                acc[r][2]=__fadd_rn(acc[r][2],__fmul_rn(h4.w,w3.z));
                acc[r][3]=__fadd_rn(acc[r][3],__fmul_rn(h4.x,w0.w));
                acc[r][3]=__fadd_rn(acc[r][3],__fmul_rn(h4.y,w1.w));
                acc[r][3]=__fadd_rn(acc[r][3],__fmul_rn(h4.z,w2.w));
                acc[r][3]=__fadd_rn(acc[r][3],__fmul_rn(h4.w,w3.w));
            }
        }
        // No barrier here: writers below == readers above (group Bm, same wave).
#pragma unroll
        for (int r = 0; r < RPB; r++) {
            const float a = acc[r][0], b = acc[r][1], c = acc[r][2], d = acc[r][3];
            const float s0 = __fadd_rn(a,b), d0 = __fsub_rn(a,b);
            const float s1 = __fadd_rn(c,d), d1 = __fsub_rn(c,d);
            *reinterpret_cast<float4*>(lds + r*RSTR + Bm*BSTR + j0) =
                f4(__fadd_rn(s0,s1), __fadd_rn(d0,d1), __fsub_rn(s0,s1), __fsub_rn(d0,d1));
        }
        __syncthreads();

        {
            const int rr = t >> 5, bb = t & 31;
            float* bp = lds + rr*RSTR + bb*BSTR;
            float4 v[8];
#pragma unroll
            for (int k = 0; k < 8; k++) v[k] = *reinterpret_cast<float4*>(bp + 4*k);
#pragma unroll
            for (int m = 1; m < 8; m <<= 1) {
#pragma unroll
                for (int k = 0; k < 8; k++) if (!(k & m)) {
                    const float4 a = v[k], b = v[k | m];
                    v[k]     = f4(__fadd_rn(a.x,b.x), __fadd_rn(a.y,b.y),
                                  __fadd_rn(a.z,b.z), __fadd_rn(a.w,b.w));
                    v[k | m] = f4(__fsub_rn(a.x,b.x), __fsub_rn(a.y,b.y),
                                  __fsub_rn(a.z,b.z), __fsub_rn(a.w,b.w));
                }
            }
#pragma unroll
            for (int k = 0; k < 8; k++) *reinterpret_cast<float4*>(bp + 4*k) = v[k];
        }
        __syncthreads();

        {
            const int rr = t >> 5, J = t & 31;
            float* bp = lds + rr*RSTR + J;
            float g[32];
#pragma unroll
            for (int k = 0; k < 32; k++) g[k] = bp[k*BSTR];
#pragma unroll
            for (int m = 1; m < 32; m <<= 1) {
#pragma unroll
                for (int k = 0; k < 32; k++) if (!(k & m)) {
                    const float a = g[k], b = g[k | m];
                    g[k] = __fadd_rn(a,b); g[k | m] = __fsub_rn(a,b);
                }
            }
#pragma unroll
            for (int k = 0; k < 32; k++) bp[k*BSTR] = g[k];
        }
        __syncthreads();
    }

    // ---------- Phase E: z = (0.7*h) + (0.3*xn) + bias, p < 320 ----------
    {
        const float c0 = 0.7f, c1 = 0.3f;
#pragma unroll
        for (int u = 0; u < 2; u++) {
            const int r = wv + 4*u;
            {
                const int p = 4*lane;
                const float4 zb = *reinterpret_cast<const float4*>(ZB + p);
                float* zp = lds + r*RSTR + (p >> 5)*BSTR + (p & 31);
                float4 h4 = *reinterpret_cast<float4*>(zp);
                h4.x = __fadd_rn(__fadd_rn(__fmul_rn(c0,h4.x), __fmul_rn(c1,xn0[u].x)), zb.x);
                h4.y = __fadd_rn(__fadd_rn(__fmul_rn(c0,h4.y), __fmul_rn(c1,xn0[u].y)), zb.y);
                h4.z = __fadd_rn(__fadd_rn(__fmul_rn(c0,h4.z), __fmul_rn(c1,xn0[u].z)), zb.z);
                h4.w = __fadd_rn(__fadd_rn(__fmul_rn(c0,h4.w), __fmul_rn(c1,xn0[u].w)), zb.w);
                *reinterpret_cast<float4*>(zp) = h4;
            }
            if (lane < 16) {
                const int p = 256 + 4*lane;
                const float4 zb = *reinterpret_cast<const float4*>(ZB + p);
                float* zp = lds + r*RSTR + (p >> 5)*BSTR + (p & 31);
                float4 h4 = *reinterpret_cast<float4*>(zp);
                h4.x = __fadd_rn(__fadd_rn(__fmul_rn(c0,h4.x), __fmul_rn(c1,xn1[u].x)), zb.x);
                h4.y = __fadd_rn(__fadd_rn(__fmul_rn(c0,h4.y), __fmul_rn(c1,xn1[u].y)), zb.y);
                h4.z = __fadd_rn(__fadd_rn(__fmul_rn(c0,h4.z), __fmul_rn(c1,xn1[u].z)), zb.z);
                h4.w = __fadd_rn(__fadd_rn(__fmul_rn(c0,h4.w), __fmul_rn(c1,xn1[u].w)), zb.w);
                *reinterpret_cast<float4*>(zp) = h4;
            }
        }
    }
    __syncthreads();

    // ---------- Phase F: codes & scores ----------
    {
        const int r = t >> 5, T = t & 31;
        int code = 0; float sc = 1.f;
#pragma unroll
        for (int d = 0; d < CODE_LEN; d++) {
            const int p = T*CODE_LEN + d;
            const float z = lds[r*RSTR + (p >> 5)*BSTR + (p & 31)];
            if (z > 0.f) code |= (1 << d);
            sc *= 1.f / (1.f + expf(-fabsf(z)));
        }
        if constexpr (SPLIT) {
            SC[(size_t)row0 * NUM_TABLE + t] = sc;
            CD[(size_t)row0 * NUM_TABLE + t] = code;
        } else {
            l_sc[t] = sc;
            l_cd[t] = code;
        }
    }

    // ---------- Fallback-only: fp32 gather in-kernel (proven R3 path) ----------
    if constexpr (!SPLIT) {
        __syncthreads();
        float4 ob[4];
#pragma unroll
        for (int q = 0; q < 4; q++)
            ob[q] = *reinterpret_cast<const float4*>(OB + q*256 + 4*lane);
#pragma unroll
        for (int u = 0; u < 2; u++) {
            const int r = wv + 4*u;
            float4 o[4];
#pragma unroll
            for (int q = 0; q < 4; q++) o[q] = ob[q];
#pragma unroll 4
            for (int T = 0; T < NUM_TABLE; T++) {
                const float sc  = l_sc[r*NUM_TABLE + T];
                const int code  = l_cd[r*NUM_TABLE + T];
                const float* tbf = TBL + ((size_t)(T*1024 + code)) * 1024;
#pragma unroll
                for (int q = 0; q < 4; q++) {
                    const float4 tv = *reinterpret_cast<const float4*>(tbf + q*256 + 4*lane);
                    o[q].x += sc * tv.x; o[q].y += sc * tv.y;
                    o[q].z += sc * tv.z; o[q].w += sc * tv.w;
                }
            }
            float* orow = OUT + (size_t)(row0 + r) * HIDDEN;
#pragma unroll
            for (int q = 0; q < 4; q++)
                *reinterpret_cast<float4*>(orow + q*256 + 4*lane) = o[q];
        }
    }
}

// ============================================================================
// K2: fp16 gather. One wave per row; lane owns halves [lane*8..+7] and
// [512+lane*8..+7]. 8-table groups as ONE straight-line body: issue all 16
// 16B loads into a flat va[16] (static indices only — no double-buffer, no
// runtime-indexed arrays), then consume. 16 loads in flight per wave.
// ============================================================================
__global__ __launch_bounds__(256, 4) void gather_kernel(
    const __half* __restrict__ TBL16,
    const float* __restrict__ SC,
    const int*   __restrict__ CD,
    const float* __restrict__ OB,
    float* __restrict__ OUT)
{
    __shared__ float s_sc[4 * NUM_TABLE];
    __shared__ int   s_cd[4 * NUM_TABLE];
    const int t = threadIdx.x, lane = t & 63, wv = t >> 6;
    const int row0 = blockIdx.x * 4;

    if (t < 128) {
        s_sc[t] = SC[(size_t)row0 * NUM_TABLE + t];
        s_cd[t] = CD[(size_t)row0 * NUM_TABLE + t];
    }
    __syncthreads();

    float4 o[4];
    o[0] = *reinterpret_cast<const float4*>(OB + lane*8);
    o[1] = *reinterpret_cast<const float4*>(OB + lane*8 + 4);
    o[2] = *reinterpret_cast<const float4*>(OB + 512 + lane*8);
    o[3] = *reinterpret_cast<const float4*>(OB + 512 + lane*8 + 4);

#pragma unroll 1
    for (int Tg = 0; Tg < NUM_TABLE; Tg += 8) {
        uint4 va[16];
        float sc[8];
        // ---- issue phase: 16 loads in flight ----
#pragma unroll
        for (int k = 0; k < 8; k++) {
            const int T = Tg + k;
            sc[k] = s_sc[wv*NUM_TABLE + T];
            const int code = s_cd[wv*NUM_TABLE + T];
            const __half* tb = TBL16 + (((size_t)(T*1024 + code)) << 10);
            va[2*k]   = *reinterpret_cast<const uint4*>(tb + lane*8);
            va[2*k+1] = *reinterpret_cast<const uint4*>(tb + 512 + lane*8);
        }
        // ---- consume phase ----
#pragma unroll
        for (int k = 0; k < 8; k++) {
            const __half2* h0 = reinterpret_cast<const __half2*>(&va[2*k]);
            const __half2* h1 = reinterpret_cast<const __half2*>(&va[2*k+1]);
            const float s = sc[k];
            float2 f;
            f = __half22float2(h0[0]); o[0].x += s*f.x; o[0].y += s*f.y;
            f = __half22float2(h0[1]); o[0].z += s*f.x; o[0].w += s*f.y;
            f = __half22float2(h0[2]); o[1].x += s*f.x; o[1].y += s*f.y;
            f = __half22float2(h0[3]); o[1].z += s*f.x; o[1].w += s*f.y;
            f = __half22float2(h1[0]); o[2].x += s*f.x; o[2].y += s*f.y;
            f = __half22float2(h1[1]); o[2].z += s*f.x; o[2].w += s*f.y;
            f = __half22float2(h1[2]); o[3].x += s*f.x; o[3].y += s*f.y;
            f = __half22float2(h1[3]); o[3].z += s*f.x; o[3].w += s*f.y;
        }
    }

    float* orow = OUT + (size_t)(row0 + wv) * HIDDEN;
    *reinterpret_cast<float4*>(orow + lane*8)           = o[0];
    *reinterpret_cast<float4*>(orow + lane*8 + 4)       = o[1];
    *reinterpret_cast<float4*>(orow + 512 + lane*8)     = o[2];
    *reinterpret_cast<float4*>(orow + 512 + lane*8 + 4) = o[3];
}

extern "C" void kernel_launch(void* const* d_in, const int* in_sizes, int n_in,
                              void* d_out, int out_size, void* d_ws, size_t ws_size,
                              hipStream_t stream) {
    const float* X   = (const float*)d_in[0];
    const float* G   = (const float*)d_in[1];
    const float* Bt  = (const float*)d_in[2];
    const float* W   = (const float*)d_in[3];
    const float* ZB  = (const float*)d_in[4];
    const float* TBL = (const float*)d_in[5];
    const float* OB  = (const float*)d_in[6];
    float* OUT = (float*)d_out;

    const int rows = in_sizes[0] / HIDDEN;     // 8192
    const int grid = rows / RPB;               // 1024 blocks

    // ws layout: [tables fp16: 64 MiB][scores: rows*32 f32][codes: rows*32 i32]
    const size_t tbl_bytes = (size_t)TBL_ELEMS * sizeof(__half);
    const size_t sc_bytes  = (size_t)rows * NUM_TABLE * sizeof(float);
    const size_t need = tbl_bytes + 2 * sc_bytes;
    __half* TBL16 = (__half*)d_ws;
    float*  SC    = (float*)((char*)d_ws + tbl_bytes);
    int*    CD    = (int*)((char*)d_ws + tbl_bytes + sc_bytes);

    if (ws_size >= need && grid == 1024) {
        hipLaunchKernelGGL(compute_kernel<true>, dim3(grid), dim3(256), 0, stream,
                           X, G, Bt, W, ZB, TBL, OB, OUT, TBL16, SC, CD);
        hipLaunchKernelGGL(gather_kernel, dim3(rows / 4), dim3(256), 0, stream,
                           TBL16, SC, CD, OB, OUT);
    } else {
        // proven R3 monolithic fp32 path
        hipLaunchKernelGGL(compute_kernel<false>, dim3(grid), dim3(256), 0, stream,
                           X, G, Bt, W, ZB, TBL, OB, OUT, TBL16, SC, CD);
    }
}

// Round 3
// 332.616 us; speedup vs baseline: 1.4627x; 1.0421x over previous
//
#include <hip/hip_runtime.h>
#include <hip/hip_fp16.h>
#include <math.h>

#define HIDDEN 1024
#define CODE_LEN 10
#define NUM_TABLE 32
#define RPB 8            // rows per block (K1)
#define BSTR 36          // padded words per 32-elem block in LDS
#define RSTR (32*BSTR)   // 1152 words per row
#define TBL_ELEMS (32u*1024u*1024u)   // 33,554,432

__device__ __forceinline__ float4 f4(float a, float b, float c, float d) {
    return make_float4(a, b, c, d);
}

// ============================================================================
// K1: cast tables fp32->fp16 + bit-exact LN/BH4/codes -> SC/CD in ws.
// Cast is STAGGERED by block parity: even blocks cast before the phases
// (memory pipe busy while odd blocks' VALU phases run), odd blocks cast after
// phase F. Zero registers held across phases — per-CU overlap of mem vs VALU.
// CAST=false variant used by the monolithic fallback path.
// ============================================================================
template <bool SPLIT>
__global__ __launch_bounds__(256, 4) void compute_kernel(
    const float* __restrict__ X,   // [rows,1024]
    const float* __restrict__ G,   // [1024] ln_gamma
    const float* __restrict__ Bt,  // [1024] ln_beta
    const float* __restrict__ W,   // [1,4,32,32,32] bh4_weight
    const float* __restrict__ ZB,  // [320] bh4_bias
    const float* __restrict__ TBL, // [32*1024,1024] tables flat (fp32)
    const float* __restrict__ OB,  // [1024] out_bias
    float* __restrict__ OUT,       // [rows,1024]
    __half* __restrict__ TBL16,    // ws: fp16 tables
    float* __restrict__ SC,        // ws: [rows*32] scores
    int*   __restrict__ CD)        // ws: [rows*32] codes
{
    __shared__ float lds[RPB * RSTR];          // 36864 B
    __shared__ float l_sc[RPB * NUM_TABLE];    // only used by !SPLIT path
    __shared__ int   l_cd[RPB * NUM_TABLE];

    const int t    = threadIdx.x;
    const int lane = t & 63;
    const int wv   = t >> 6;
    const int row0 = blockIdx.x * RPB;

    auto do_cast = [&]() {
        const float* src = TBL   + (size_t)blockIdx.x * 32768;
        __half*      dst = TBL16 + (size_t)blockIdx.x * 32768;
#pragma unroll
        for (int k = 0; k < 16; k++) {
            const int idx = (k*256 + t) * 8;
            const float4 a = *reinterpret_cast<const float4*>(src + idx);
            const float4 b = *reinterpret_cast<const float4*>(src + idx + 4);
            union { uint4 u4; __half2 h2[4]; } pk;
            pk.h2[0] = __floats2half2_rn(a.x, a.y);
            pk.h2[1] = __floats2half2_rn(a.z, a.w);
            pk.h2[2] = __floats2half2_rn(b.x, b.y);
            pk.h2[3] = __floats2half2_rn(b.z, b.w);
            *reinterpret_cast<uint4*>(dst + idx) = pk.u4;
        }
    };

    // ---------- Phase 0 (SPLIT, even blocks): cast table slice fp32->fp16 ----------
    if constexpr (SPLIT) {
        if ((blockIdx.x & 1) == 0) do_cast();
    }

    // ---------- Phase A: load raw x into padded LDS ----------
#pragma unroll
    for (int u = 0; u < 2; u++) {
        const int r = wv + 4*u;
        const float* xr = X + (size_t)(row0 + r) * HIDDEN;
#pragma unroll
        for (int q = 0; q < 4; q++) {
            const int p = q*256 + 4*lane;
            const float4 v = *reinterpret_cast<const float4*>(xr + p);
            *reinterpret_cast<float4*>(lds + r*RSTR + (p >> 5)*BSTR + (p & 31)) = v;
        }
    }

    // ---------- Phase B: numpy-pairwise mean/var (bit-exact np.mean order) ----------
    float mu0, mu4, rs0, rs4;
    {
        float bsum = 0.f;
        if (lane < 16) {
            const int row = wv + 4*(lane >> 3);
            const int blk = lane & 7;
            const float* bp = lds + row*RSTR + blk*4*BSTR;
            float r8[8];
            {
                const float4 f0 = *reinterpret_cast<const float4*>(bp);
                const float4 f1 = *reinterpret_cast<const float4*>(bp + 4);
                r8[0]=f0.x; r8[1]=f0.y; r8[2]=f0.z; r8[3]=f0.w;
                r8[4]=f1.x; r8[5]=f1.y; r8[6]=f1.z; r8[7]=f1.w;
            }
#pragma unroll
            for (int m = 1; m < 16; m++) {
                const int p = 8*m;
                const float* qp = bp + (p >> 5)*BSTR + (p & 31);
                const float4 f0 = *reinterpret_cast<const float4*>(qp);
                const float4 f1 = *reinterpret_cast<const float4*>(qp + 4);
                r8[0]=__fadd_rn(r8[0],f0.x); r8[1]=__fadd_rn(r8[1],f0.y);
                r8[2]=__fadd_rn(r8[2],f0.z); r8[3]=__fadd_rn(r8[3],f0.w);
                r8[4]=__fadd_rn(r8[4],f1.x); r8[5]=__fadd_rn(r8[5],f1.y);
                r8[6]=__fadd_rn(r8[6],f1.z); r8[7]=__fadd_rn(r8[7],f1.w);
            }
            bsum = __fadd_rn(__fadd_rn(__fadd_rn(r8[0],r8[1]), __fadd_rn(r8[2],r8[3])),
                             __fadd_rn(__fadd_rn(r8[4],r8[5]), __fadd_rn(r8[6],r8[7])));
        }
        float v = bsum;
        v = __fadd_rn(v, __shfl_xor(v, 1, 64));
        v = __fadd_rn(v, __shfl_xor(v, 2, 64));
        v = __fadd_rn(v, __shfl_xor(v, 4, 64));
        mu0 = __fmul_rn(__shfl(v, 0, 64), 0.0009765625f);
        mu4 = __fmul_rn(__shfl(v, 8, 64), 0.0009765625f);

        float bss = 0.f;
        if (lane < 16) {
            const int row = wv + 4*(lane >> 3);
            const float mu = (lane & 8) ? mu4 : mu0;
            const int blk = lane & 7;
            const float* bp = lds + row*RSTR + blk*4*BSTR;
            float r8[8];
            {
                const float4 f0 = *reinterpret_cast<const float4*>(bp);
                const float4 f1 = *reinterpret_cast<const float4*>(bp + 4);
                float d;
                d=__fsub_rn(f0.x,mu); r8[0]=__fmul_rn(d,d);
                d=__fsub_rn(f0.y,mu); r8[1]=__fmul_rn(d,d);
                d=__fsub_rn(f0.z,mu); r8[2]=__fmul_rn(d,d);
                d=__fsub_rn(f0.w,mu); r8[3]=__fmul_rn(d,d);
                d=__fsub_rn(f1.x,mu); r8[4]=__fmul_rn(d,d);
                d=__fsub_rn(f1.y,mu); r8[5]=__fmul_rn(d,d);
                d=__fsub_rn(f1.z,mu); r8[6]=__fmul_rn(d,d);
                d=__fsub_rn(f1.w,mu); r8[7]=__fmul_rn(d,d);
            }
#pragma unroll
            for (int m = 1; m < 16; m++) {
                const int p = 8*m;
                const float* qp = bp + (p >> 5)*BSTR + (p & 31);
                const float4 f0 = *reinterpret_cast<const float4*>(qp);
                const float4 f1 = *reinterpret_cast<const float4*>(qp + 4);
                float d;
                d=__fsub_rn(f0.x,mu); r8[0]=__fadd_rn(r8[0],__fmul_rn(d,d));
                d=__fsub_rn(f0.y,mu); r8[1]=__fadd_rn(r8[1],__fmul_rn(d,d));
                d=__fsub_rn(f0.z,mu); r8[2]=__fadd_rn(r8[2],__fmul_rn(d,d));
                d=__fsub_rn(f0.w,mu); r8[3]=__fadd_rn(r8[3],__fmul_rn(d,d));
                d=__fsub_rn(f1.x,mu); r8[4]=__fadd_rn(r8[4],__fmul_rn(d,d));
                d=__fsub_rn(f1.y,mu); r8[5]=__fadd_rn(r8[5],__fmul_rn(d,d));
                d=__fsub_rn(f1.z,mu); r8[6]=__fadd_rn(r8[6],__fmul_rn(d,d));
                d=__fsub_rn(f1.w,mu); r8[7]=__fadd_rn(r8[7],__fmul_rn(d,d));
            }
            bss = __fadd_rn(__fadd_rn(__fadd_rn(r8[0],r8[1]), __fadd_rn(r8[2],r8[3])),
                            __fadd_rn(__fadd_rn(r8[4],r8[5]), __fadd_rn(r8[6],r8[7])));
        }
        float v2 = bss;
        v2 = __fadd_rn(v2, __shfl_xor(v2, 1, 64));
        v2 = __fadd_rn(v2, __shfl_xor(v2, 2, 64));
        v2 = __fadd_rn(v2, __shfl_xor(v2, 4, 64));
        const float var0 = __fmul_rn(__shfl(v2, 0, 64), 0.0009765625f);
        const float var4 = __fmul_rn(__shfl(v2, 8, 64), 0.0009765625f);
        rs0 = __fdiv_rn(1.0f, __fsqrt_rn(__fadd_rn(var0, 1e-12f)));
        rs4 = __fdiv_rn(1.0f, __fsqrt_rn(__fadd_rn(var4, 1e-12f)));
    }

    // ---------- Phase C: xn = ((x-mu)*rstd)*gamma + beta, in place ----------
    float4 xn0[2], xn1[2];
    {
        float4 g4[4], b4[4];
#pragma unroll
        for (int q = 0; q < 4; q++) {
            g4[q] = *reinterpret_cast<const float4*>(G  + q*256 + 4*lane);
            b4[q] = *reinterpret_cast<const float4*>(Bt + q*256 + 4*lane);
        }
#pragma unroll
        for (int u = 0; u < 2; u++) {
            const int r = wv + 4*u;
            const float mu = u ? mu4 : mu0;
            const float rstd = u ? rs4 : rs0;
#pragma unroll
            for (int q = 0; q < 4; q++) {
                const int p = q*256 + 4*lane;
                float* ptr = lds + r*RSTR + (p >> 5)*BSTR + (p & 31);
                const float4 x4 = *reinterpret_cast<float4*>(ptr);
                float4 xn;
                xn.x = __fadd_rn(__fmul_rn(__fmul_rn(__fsub_rn(x4.x, mu), rstd), g4[q].x), b4[q].x);
                xn.y = __fadd_rn(__fmul_rn(__fmul_rn(__fsub_rn(x4.y, mu), rstd), g4[q].y), b4[q].y);
                xn.z = __fadd_rn(__fmul_rn(__fmul_rn(__fsub_rn(x4.z, mu), rstd), g4[q].z), b4[q].z);
                xn.w = __fadd_rn(__fmul_rn(__fmul_rn(__fsub_rn(x4.w, mu), rstd), g4[q].w), b4[q].w);
                *reinterpret_cast<float4*>(ptr) = xn;
                if (q == 0) xn0[u] = xn;
                if (q == 1) xn1[u] = xn;
            }
        }
    }
    __syncthreads();

    // ---------- Phase D: 4 BH4 stages, np-einsum order + ascending FWHT ----------
    const int Bm = t >> 3;
    const int j0 = (t & 7) * 4;
#pragma unroll 1
    for (int s = 0; s < 4; s++) {
        float acc[RPB][4];
#pragma unroll
        for (int r = 0; r < RPB; r++)
#pragma unroll
            for (int c = 0; c < 4; c++) acc[r][c] = 0.0f;
        const float* Wb = W + s*32768 + Bm*1024 + j0;
#pragma unroll 2
        for (int iq = 0; iq < 8; iq++) {
            const float4 w0 = *reinterpret_cast<const float4*>(Wb + (iq*4 + 0)*32);
            const float4 w1 = *reinterpret_cast<const float4*>(Wb + (iq*4 + 1)*32);
            const float4 w2 = *reinterpret_cast<const float4*>(Wb + (iq*4 + 2)*32);
            const float4 w3 = *reinterpret_cast<const float4*>(Wb + (iq*4 + 3)*32);
#pragma unroll
            for (int r = 0; r < RPB; r++) {
                const float4 h4 = *reinterpret_cast<const float4*>(lds + r*RSTR + Bm*BSTR + iq*4);
                acc[r][0]=__fadd_rn(acc[r][0],__fmul_rn(h4.x,w0.x));
                acc[r][0]=__fadd_rn(acc[r][0],__fmul_rn(h4.y,w1.x));
                acc[r][0]=__fadd_rn(acc[r][0],__fmul_rn(h4.z,w2.x));
                acc[r][0]=__fadd_rn(acc[r][0],__fmul_rn(h4.w,w3.x));
                acc[r][1]=__fadd_rn(acc[r][1],__fmul_rn(h4.x,w0.y));
                acc[r][1]=__fadd_rn(acc[r][1],__fmul_rn(h4.y,w1.y));
                acc[r][1]=__fadd_rn(acc[r][1],__fmul_rn(h4.z,w2.y));
                acc[r][1]=__fadd_rn(acc[r][1],__fmul_rn(h4.w,w3.y));
                acc[r][2]=__fadd_rn(acc[r][2],__fmul_rn(h4.x,w0.z));
                acc[r][2]=__fadd_rn(acc[r][2],__fmul_rn(h4.y,w1.z));
                acc[r][2]=__fadd_rn(acc[r][2],__fmul_rn(h4.z,w2.z));
                acc[r][2]=__fadd_rn(acc[r][2],__fmul_rn(h4.w,w3.z));
                acc[r][3]=__fadd_rn(acc[r][3],__fmul_rn(h4.x,w0.w));
                acc[r][3]=__fadd_rn(acc[r][3],__fmul_rn(h4.y,w1.w));
                acc[r][3]=__fadd_rn(acc[r][3],__fmul_rn(h4.z,w2.w));
                acc[r][3]=__fadd_rn(acc[r][3],__fmul_rn(h4.w,w3.w));
            }
        }
        // No barrier here: writers below == readers above (group Bm, same wave).
#pragma unroll
        for (int r = 0; r < RPB; r++) {
            const float a = acc[r][0], b = acc[r][1], c = acc[r][2], d = acc[r][3];
            const float s0 = __fadd_rn(a,b), d0 = __fsub_rn(a,b);
            const float s1 = __fadd_rn(c,d), d1 = __fsub_rn(c,d);
            *reinterpret_cast<float4*>(lds + r*RSTR + Bm*BSTR + j0) =
                f4(__fadd_rn(s0,s1), __fadd_rn(d0,d1), __fsub_rn(s0,s1), __fsub_rn(d0,d1));
        }
        __syncthreads();

        {
            const int rr = t >> 5, bb = t & 31;
            float* bp = lds + rr*RSTR + bb*BSTR;
            float4 v[8];
#pragma unroll
            for (int k = 0; k < 8; k++) v[k] = *reinterpret_cast<float4*>(bp + 4*k);
#pragma unroll
            for (int m = 1; m < 8; m <<= 1) {
#pragma unroll
                for (int k = 0; k < 8; k++) if (!(k & m)) {
                    const float4 a = v[k], b = v[k | m];
                    v[k]     = f4(__fadd_rn(a.x,b.x), __fadd_rn(a.y,b.y),
                                  __fadd_rn(a.z,b.z), __fadd_rn(a.w,b.w));
                    v[k | m] = f4(__fsub_rn(a.x,b.x), __fsub_rn(a.y,b.y),
                                  __fsub_rn(a.z,b.z), __fsub_rn(a.w,b.w));
                }
            }
#pragma unroll
            for (int k = 0; k < 8; k++) *reinterpret_cast<float4*>(bp + 4*k) = v[k];
        }
        __syncthreads();

        {
            const int rr = t >> 5, J = t & 31;
            float* bp = lds + rr*RSTR + J;
            float g[32];
#pragma unroll
            for (int k = 0; k < 32; k++) g[k] = bp[k*BSTR];
#pragma unroll
            for (int m = 1; m < 32; m <<= 1) {
#pragma unroll
                for (int k = 0; k < 32; k++) if (!(k & m)) {
                    const float a = g[k], b = g[k | m];
                    g[k] = __fadd_rn(a,b); g[k | m] = __fsub_rn(a,b);
                }
            }
#pragma unroll
            for (int k = 0; k < 32; k++) bp[k*BSTR] = g[k];
        }
        __syncthreads();
    }

    // ---------- Phase E: z = (0.7*h) + (0.3*xn) + bias, p < 320 ----------
    {
        const float c0 = 0.7f, c1 = 0.3f;
#pragma unroll
        for (int u = 0; u < 2; u++) {
            const int r = wv + 4*u;
            {
                const int p = 4*lane;
                const float4 zb = *reinterpret_cast<const float4*>(ZB + p);
                float* zp = lds + r*RSTR + (p >> 5)*BSTR + (p & 31);
                float4 h4 = *reinterpret_cast<float4*>(zp);
                h4.x = __fadd_rn(__fadd_rn(__fmul_rn(c0,h4.x), __fmul_rn(c1,xn0[u].x)), zb.x);
                h4.y = __fadd_rn(__fadd_rn(__fmul_rn(c0,h4.y), __fmul_rn(c1,xn0[u].y)), zb.y);
                h4.z = __fadd_rn(__fadd_rn(__fmul_rn(c0,h4.z), __fmul_rn(c1,xn0[u].z)), zb.z);
                h4.w = __fadd_rn(__fadd_rn(__fmul_rn(c0,h4.w), __fmul_rn(c1,xn0[u].w)), zb.w);
                *reinterpret_cast<float4*>(zp) = h4;
            }
            if (lane < 16) {
                const int p = 256 + 4*lane;
                const float4 zb = *reinterpret_cast<const float4*>(ZB + p);
                float* zp = lds + r*RSTR + (p >> 5)*BSTR + (p & 31);
                float4 h4 = *reinterpret_cast<float4*>(zp);
                h4.x = __fadd_rn(__fadd_rn(__fmul_rn(c0,h4.x), __fmul_rn(c1,xn1[u].x)), zb.x);
                h4.y = __fadd_rn(__fadd_rn(__fmul_rn(c0,h4.y), __fmul_rn(c1,xn1[u].y)), zb.y);
                h4.z = __fadd_rn(__fadd_rn(__fmul_rn(c0,h4.z), __fmul_rn(c1,xn1[u].z)), zb.z);
                h4.w = __fadd_rn(__fadd_rn(__fmul_rn(c0,h4.w), __fmul_rn(c1,xn1[u].w)), zb.w);
                *reinterpret_cast<float4*>(zp) = h4;
            }
        }
    }
    __syncthreads();

    // ---------- Phase F: codes & scores ----------
    {
        const int r = t >> 5, T = t & 31;
        int code = 0; float sc = 1.f;
#pragma unroll
        for (int d = 0; d < CODE_LEN; d++) {
            const int p = T*CODE_LEN + d;
            const float z = lds[r*RSTR + (p >> 5)*BSTR + (p & 31)];
            if (z > 0.f) code |= (1 << d);
            sc *= 1.f / (1.f + expf(-fabsf(z)));
        }
        if constexpr (SPLIT) {
            SC[(size_t)row0 * NUM_TABLE + t] = sc;
            CD[(size_t)row0 * NUM_TABLE + t] = code;
        } else {
            l_sc[t] = sc;
            l_cd[t] = code;
        }
    }

    // ---------- Phase 0' (SPLIT, odd blocks): cast table slice fp32->fp16 ----------
    if constexpr (SPLIT) {
        if (blockIdx.x & 1) do_cast();
    }

    // ---------- Fallback-only: fp32 gather in-kernel (proven R3 path) ----------
    if constexpr (!SPLIT) {
        __syncthreads();
        float4 ob[4];
#pragma unroll
        for (int q = 0; q < 4; q++)
            ob[q] = *reinterpret_cast<const float4*>(OB + q*256 + 4*lane);
#pragma unroll
        for (int u = 0; u < 2; u++) {
            const int r = wv + 4*u;
            float4 o[4];
#pragma unroll
            for (int q = 0; q < 4; q++) o[q] = ob[q];
#pragma unroll 4
            for (int T = 0; T < NUM_TABLE; T++) {
                const float sc  = l_sc[r*NUM_TABLE + T];
                const int code  = l_cd[r*NUM_TABLE + T];
                const float* tbf = TBL + ((size_t)(T*1024 + code)) * 1024;
#pragma unroll
                for (int q = 0; q < 4; q++) {
                    const float4 tv = *reinterpret_cast<const float4*>(tbf + q*256 + 4*lane);
                    o[q].x += sc * tv.x; o[q].y += sc * tv.y;
                    o[q].z += sc * tv.z; o[q].w += sc * tv.w;
                }
            }
            float* orow = OUT + (size_t)(row0 + r) * HIDDEN;
#pragma unroll
            for (int q = 0; q < 4; q++)
                *reinterpret_cast<float4*>(orow + q*256 + 4*lane) = o[q];
        }
    }
}

// ============================================================================
// K2: fp16 gather. One wave per row; lane owns halves [lane*8..+7] and
// [512+lane*8..+7]. 8-table groups: issue all 16 16B loads, then a
// sched_barrier(0) pins the issue/consume split so the compiler CANNOT
// re-interleave loads into the consume phase (R2 failure: VGPR=64 proved it
// re-serialized to ~8 in flight). Forces 16 loads genuinely outstanding.
// ============================================================================
__global__ __launch_bounds__(256, 4) void gather_kernel(
    const __half* __restrict__ TBL16,
    const float* __restrict__ SC,
    const int*   __restrict__ CD,
    const float* __restrict__ OB,
    float* __restrict__ OUT)
{
    __shared__ float s_sc[4 * NUM_TABLE];
    __shared__ int   s_cd[4 * NUM_TABLE];
    const int t = threadIdx.x, lane = t & 63, wv = t >> 6;
    const int row0 = blockIdx.x * 4;

    if (t < 128) {
        s_sc[t] = SC[(size_t)row0 * NUM_TABLE + t];
        s_cd[t] = CD[(size_t)row0 * NUM_TABLE + t];
    }
    __syncthreads();

    float4 o[4];
    o[0] = *reinterpret_cast<const float4*>(OB + lane*8);
    o[1] = *reinterpret_cast<const float4*>(OB + lane*8 + 4);
    o[2] = *reinterpret_cast<const float4*>(OB + 512 + lane*8);
    o[3] = *reinterpret_cast<const float4*>(OB + 512 + lane*8 + 4);

#pragma unroll 1
    for (int Tg = 0; Tg < NUM_TABLE; Tg += 8) {
        uint4 va[16];
        float sc[8];
        // ---- issue phase: 16 loads in flight ----
#pragma unroll
        for (int k = 0; k < 8; k++) {
            const int T = Tg + k;
            sc[k] = s_sc[wv*NUM_TABLE + T];
            const int code = s_cd[wv*NUM_TABLE + T];
            const __half* tb = TBL16 + (((size_t)(T*1024 + code)) << 10);
            va[2*k]   = *reinterpret_cast<const uint4*>(tb + lane*8);
            va[2*k+1] = *reinterpret_cast<const uint4*>(tb + 512 + lane*8);
        }
        // pin the split: no load may sink below, no consume may hoist above
        __builtin_amdgcn_sched_barrier(0);
        // ---- consume phase ----
#pragma unroll
        for (int k = 0; k < 8; k++) {
            const __half2* h0 = reinterpret_cast<const __half2*>(&va[2*k]);
            const __half2* h1 = reinterpret_cast<const __half2*>(&va[2*k+1]);
            const float s = sc[k];
            float2 f;
            f = __half22float2(h0[0]); o[0].x += s*f.x; o[0].y += s*f.y;
            f = __half22float2(h0[1]); o[0].z += s*f.x; o[0].w += s*f.y;
            f = __half22float2(h0[2]); o[1].x += s*f.x; o[1].y += s*f.y;
            f = __half22float2(h0[3]); o[1].z += s*f.x; o[1].w += s*f.y;
            f = __half22float2(h1[0]); o[2].x += s*f.x; o[2].y += s*f.y;
            f = __half22float2(h1[1]); o[2].z += s*f.x; o[2].w += s*f.y;
            f = __half22float2(h1[2]); o[3].x += s*f.x; o[3].y += s*f.y;
            f = __half22float2(h1[3]); o[3].z += s*f.x; o[3].w += s*f.y;
        }
    }

    float* orow = OUT + (size_t)(row0 + wv) * HIDDEN;
    *reinterpret_cast<float4*>(orow + lane*8)           = o[0];
    *reinterpret_cast<float4*>(orow + lane*8 + 4)       = o[1];
    *reinterpret_cast<float4*>(orow + 512 + lane*8)     = o[2];
    *reinterpret_cast<float4*>(orow + 512 + lane*8 + 4) = o[3];
}

extern "C" void kernel_launch(void* const* d_in, const int* in_sizes, int n_in,
                              void* d_out, int out_size, void* d_ws, size_t ws_size,
                              hipStream_t stream) {
    const float* X   = (const float*)d_in[0];
    const float* G   = (const float*)d_in[1];
    const float* Bt  = (const float*)d_in[2];
    const float* W   = (const float*)d_in[3];
    const float* ZB  = (const float*)d_in[4];
    const float* TBL = (const float*)d_in[5];
    const float* OB  = (const float*)d_in[6];
    float* OUT = (float*)d_out;

    const int rows = in_sizes[0] / HIDDEN;     // 8192
    const int grid = rows / RPB;               // 1024 blocks

    // ws layout: [tables fp16: 64 MiB][scores: rows*32 f32][codes: rows*32 i32]
    const size_t tbl_bytes = (size_t)TBL_ELEMS * sizeof(__half);
    const size_t sc_bytes  = (size_t)rows * NUM_TABLE * sizeof(float);
    const size_t need = tbl_bytes + 2 * sc_bytes;
    __half* TBL16 = (__half*)d_ws;
    float*  SC    = (float*)((char*)d_ws + tbl_bytes);
    int*    CD    = (int*)((char*)d_ws + tbl_bytes + sc_bytes);

    if (ws_size >= need && grid == 1024) {
        hipLaunchKernelGGL(compute_kernel<true>, dim3(grid), dim3(256), 0, stream,
                           X, G, Bt, W, ZB, TBL, OB, OUT, TBL16, SC, CD);
        hipLaunchKernelGGL(gather_kernel, dim3(rows / 4), dim3(256), 0, stream,
                           TBL16, SC, CD, OB, OUT);
    } else {
        // proven R3 monolithic fp32 path
        hipLaunchKernelGGL(compute_kernel<false>, dim3(grid), dim3(256), 0, stream,
                           X, G, Bt, W, ZB, TBL, OB, OUT, TBL16, SC, CD);
    }
}